// Round 2
// 516.541 us; speedup vs baseline: 1.0492x; 1.0492x over previous
//
#include <hip/hip_runtime.h>
#include <hip/hip_bf16.h>

// Causal linear attention (ELU+1), chunked 3-pass, bf16 MFMA formulation.
// B=4, T=8192, H=16, D=64, fp32 in/out.
// ws: 4096 records (bh*NCH+c) of REC=4160 fp32: S^T[e][d] (4096) then z[d] (64).
// ws requirement: 68.2 MB.
//
// R1 changes vs previous best (resubmitted after infra timeout):
//  - k_output: one 512-thread block per FULL 128-row chunk (was 2x 64-row blocks):
//    removes the 1.5x re-read of k/v, skips fully-masked W tiles (wave-uniform).
//    W double-buffered into dead qb/kb LDS regions -> 64KB LDS, 2 blocks/CU.
//  - transposed LDS tiles (ktr/vtr/vb) built via in-register 4x4 transpose +
//    ds_write_b64 (was 16x scalar ds_write_b16 per float4, ~8-way conflicted).
//  - k_prefix: unroll 4 for memory-level parallelism.

#define EPS_ 1e-6f

constexpr int Bc  = 4;
constexpr int Tc  = 8192;
constexpr int Hc  = 16;
constexpr int Dc  = 64;
constexpr int CH  = 128;          // chunk length
constexpr int NCH = Tc / CH;      // 64
constexpr int BHc = Bc * Hc;      // 64
constexpr int REC = Dc * Dc + Dc; // 4160

typedef short  bf16x8 __attribute__((ext_vector_type(8)));  // 8 bf16 (4 VGPRs)
typedef float  f32x4  __attribute__((ext_vector_type(4)));

__device__ __forceinline__ float phi_f(float x) {
    return x > 0.f ? x + 1.f : __expf(x);   // elu(x)+1
}
__device__ __forceinline__ unsigned short f2b(float x) {
    __hip_bfloat16 b = __float2bfloat16(x);          // round-to-nearest-even
    return __builtin_bit_cast(unsigned short, b);
}
__device__ __forceinline__ float b2f(unsigned short u) {
    return __uint_as_float(((unsigned)u) << 16);     // exact
}

// ---------------- pass 1: rec = [ S^T[e][d] = sum_s v[s][e] phi(k)[s][d] ; z[d] ] ----
__global__ __launch_bounds__(256) void k_chunksum(const float* __restrict__ kin,
                                                  const float* __restrict__ vin,
                                                  float* __restrict__ ws) {
    const int chunk = blockIdx.x;            // bh*NCH + c
    const int bh = chunk >> 6, c = chunk & (NCH - 1);
    const int b  = bh >> 4,    h = bh & 15;
    const int t0 = c * CH;
    const int tid = threadIdx.x;

    __shared__ unsigned short ktr[64][136];  // phiK^T [d][s], s=0..127
    __shared__ unsigned short vtr[64][136];  // V^T    [e][s]
    __shared__ float zred[4][64];

    // stage + transpose 128 rows of k,v: each lane owns a 4x4 block
    // (rows r0..r0+3, cols c0..c0+3), transposes in registers, writes 4x b64.
    {
        const int c0 = (tid & 15) << 2;          // 0,4,...,60
        const int rl = ((tid >> 4) & 15) << 2;   // 0,4,...,60
        #pragma unroll
        for (int sh = 0; sh < 2; ++sh) {
            const int r0 = rl + sh * 64;
            unsigned short hk[4][4], hv[4][4];
            #pragma unroll
            for (int jj = 0; jj < 4; ++jj) {
                const size_t g = ((((size_t)b * Tc) + (t0 + r0 + jj)) * Hc + h) * Dc + c0;
                const float4 kk = *(const float4*)(kin + g);
                const float4 vv = *(const float4*)(vin + g);
                hk[jj][0] = f2b(phi_f(kk.x)); hk[jj][1] = f2b(phi_f(kk.y));
                hk[jj][2] = f2b(phi_f(kk.z)); hk[jj][3] = f2b(phi_f(kk.w));
                hv[jj][0] = f2b(vv.x); hv[jj][1] = f2b(vv.y);
                hv[jj][2] = f2b(vv.z); hv[jj][3] = f2b(vv.w);
            }
            #pragma unroll
            for (int j = 0; j < 4; ++j) {
                *(ushort4*)&ktr[c0 + j][r0] = make_ushort4(hk[0][j], hk[1][j], hk[2][j], hk[3][j]);
                *(ushort4*)&vtr[c0 + j][r0] = make_ushort4(hv[0][j], hv[1][j], hv[2][j], hv[3][j]);
            }
        }
    }
    __syncthreads();

    // z[d] = sum_s phiK[s][d]  (sum the bf16-rounded values, fp32 accumulate)
    {
        const int d = tid & 63, part = tid >> 6;
        float zs = 0.f;
        #pragma unroll
        for (int j = 0; j < 4; j++) {
            bf16x8 kv = *(const bf16x8*)&ktr[d][part * 32 + j * 8];
            #pragma unroll
            for (int u = 0; u < 8; u++) zs += b2f((unsigned short)kv[u]);
        }
        zred[part][d] = zs;
    }

    // MFMA: C[e][d] += V^T[e][s] * phiK[s][d]
    const int w = tid >> 6, lane = tid & 63;
    const int l15 = lane & 15, quad = lane >> 4;
    f32x4 acc[4];
    #pragma unroll
    for (int nt = 0; nt < 4; nt++) acc[nt] = (f32x4){0.f, 0.f, 0.f, 0.f};
    #pragma unroll
    for (int ks = 0; ks < 4; ks++) {
        bf16x8 a = *(const bf16x8*)&vtr[16 * w + l15][quad * 8 + ks * 32];
        #pragma unroll
        for (int nt = 0; nt < 4; nt++) {
            bf16x8 bb = *(const bf16x8*)&ktr[16 * nt + l15][quad * 8 + ks * 32];
            acc[nt] = __builtin_amdgcn_mfma_f32_16x16x32_bf16(a, bb, acc[nt], 0, 0, 0);
        }
    }
    __syncthreads();   // zred complete

    float* rec = ws + (size_t)chunk * REC;
    #pragma unroll
    for (int nt = 0; nt < 4; nt++)
        #pragma unroll
        for (int r = 0; r < 4; r++) {
            const int e = 16 * w + quad * 4 + r;
            const int d = 16 * nt + l15;
            rec[e * 64 + d] = acc[nt][r];
        }
    if (tid < 64)
        rec[4096 + tid] = zred[0][tid] + zred[1][tid] + zred[2][tid] + zred[3][tid];
}

// ---------------- pass 2: exclusive prefix over chunks (fp32, elementwise) --------
__global__ __launch_bounds__(256) void k_prefix(float* __restrict__ ws) {
    const int bh = blockIdx.x;
    const int e  = blockIdx.y * 256 + threadIdx.x;
    if (e >= REC) return;
    float* p = ws + (size_t)bh * NCH * REC + e;
    float run = 0.f;
    #pragma unroll 4
    for (int c = 0; c < NCH; ++c) {
        float x = p[(size_t)c * REC];
        p[(size_t)c * REC] = run;
        run += x;
    }
}

// ---------------- pass 3: outputs, one 512-thread block per FULL chunk ------------
__global__ __launch_bounds__(512, 4) void k_output(const float* __restrict__ qin,
                                                   const float* __restrict__ kin,
                                                   const float* __restrict__ vin,
                                                   const float* __restrict__ ws,
                                                   float* __restrict__ outp) {
    const int chunk = blockIdx.x;                // bh*NCH + c
    const int bh = chunk >> 6, c = chunk & (NCH - 1);
    const int b = bh >> 4, h = bh & 15;
    const int t0 = c * CH;
    const int tid = threadIdx.x;
    const int w = tid >> 6, lane = tid & 63;
    const int l15 = lane & 15, quad = lane >> 4;

    __shared__ unsigned short qb[128][72];  // phiQ [t][d]; cols reused as W[t][64+s']
    __shared__ unsigned short kb[128][72];  // phiK [s][d]; reused as W[t][s<64]
    __shared__ unsigned short sb[64][72];   // S^T[e][d] (prefixed, bf16)
    __shared__ unsigned short vb[64][136];  // V^T [e][s], s=0..127
    __shared__ float zsh[64];
    __shared__ float den[128];

    // ---- stage phi(q), phi(k) natural (128 rows, 512 threads: one row each 1/4) --
    {
        const int row = tid >> 2, cb = (tid & 3) << 4;
        const size_t g = ((((size_t)b * Tc) + (t0 + row)) * Hc + h) * Dc + cb;
        const float4* qp = (const float4*)(qin + g);
        const float4* kp = (const float4*)(kin + g);
        #pragma unroll
        for (int i = 0; i < 4; i++) {
            float4 qq = qp[i];
            float4 kk = kp[i];
            *(ushort4*)&qb[row][cb + 4 * i] =
                make_ushort4(f2b(phi_f(qq.x)), f2b(phi_f(qq.y)), f2b(phi_f(qq.z)), f2b(phi_f(qq.w)));
            *(ushort4*)&kb[row][cb + 4 * i] =
                make_ushort4(f2b(phi_f(kk.x)), f2b(phi_f(kk.y)), f2b(phi_f(kk.z)), f2b(phi_f(kk.w)));
        }
    }
    // ---- stage V^T via in-register 4x4 transpose (128 rows x 64 cols, one pass) --
    {
        const int c0 = (tid & 15) << 2;          // e-col group 0..60
        const int r0 = (tid >> 4) << 2;          // s-row group 0..124
        unsigned short hv[4][4];
        #pragma unroll
        for (int jj = 0; jj < 4; ++jj) {
            const size_t g = ((((size_t)b * Tc) + (t0 + r0 + jj)) * Hc + h) * Dc + c0;
            const float4 vv = *(const float4*)(vin + g);
            hv[jj][0] = f2b(vv.x); hv[jj][1] = f2b(vv.y);
            hv[jj][2] = f2b(vv.z); hv[jj][3] = f2b(vv.w);
        }
        #pragma unroll
        for (int j = 0; j < 4; ++j)
            *(ushort4*)&vb[c0 + j][r0] = make_ushort4(hv[0][j], hv[1][j], hv[2][j], hv[3][j]);
    }
    // ---- stage S^T -> sb (bf16), z -> zsh (fp32) --------------------------------
    {
        const float* rec = ws + (size_t)chunk * REC;
        #pragma unroll
        for (int i = 0; i < 2; i++) {
            const int idx = tid + i * 512;       // float4 index, 0..1023
            float4 sv = ((const float4*)rec)[idx];
            const int flat = idx * 4, e = flat >> 6, d = flat & 63;
            *(ushort4*)&sb[e][d] = make_ushort4(f2b(sv.x), f2b(sv.y), f2b(sv.z), f2b(sv.w));
        }
        if (tid < 16) {
            float4 zv = ((const float4*)(rec + 4096))[tid];
            zsh[tid * 4 + 0] = zv.x; zsh[tid * 4 + 1] = zv.y;
            zsh[tid * 4 + 2] = zv.z; zsh[tid * 4 + 3] = zv.w;
        }
    }
    __syncthreads();

    // den0 = eps + phiQ[t] . z
    if (tid < 128) {
        float s = 0.f;
        #pragma unroll
        for (int j = 0; j < 8; j++) {
            bf16x8 qv = *(const bf16x8*)&qb[tid][j * 8];
            #pragma unroll
            for (int u = 0; u < 8; u++) s += b2f((unsigned short)qv[u]) * zsh[j * 8 + u];
        }
        den[tid] = s + EPS_;
    }

    // GEMM1: acc[t][e] = phiQ[t][d] * S[d][e]   (B from S^T rows)
    f32x4 acc[4];
    #pragma unroll
    for (int nt = 0; nt < 4; nt++) acc[nt] = (f32x4){0.f, 0.f, 0.f, 0.f};
    #pragma unroll
    for (int ks = 0; ks < 2; ks++) {
        bf16x8 a = *(const bf16x8*)&qb[16 * w + l15][quad * 8 + ks * 32];
        #pragma unroll
        for (int nt = 0; nt < 4; nt++) {
            bf16x8 bb = *(const bf16x8*)&sb[16 * nt + l15][quad * 8 + ks * 32];
            acc[nt] = __builtin_amdgcn_mfma_f32_16x16x32_bf16(a, bb, acc[nt], 0, 0, 0);
        }
    }

    // GEMM2: W[t][s] = phiQ[t][d] * phiK[s][d].  Waves 0-3 (t<64) skip s>=64
    // (fully masked).  wt[nt] covers s = 16*nt + l15.
    f32x4 wt[8];
    #pragma unroll
    for (int nt = 0; nt < 8; nt++) wt[nt] = (f32x4){0.f, 0.f, 0.f, 0.f};
    #pragma unroll
    for (int ks = 0; ks < 2; ks++) {
        bf16x8 a = *(const bf16x8*)&qb[16 * w + l15][quad * 8 + ks * 32];
        #pragma unroll
        for (int nt = 0; nt < 4; nt++) {
            bf16x8 bb = *(const bf16x8*)&kb[16 * nt + l15][quad * 8 + ks * 32];
            wt[nt] = __builtin_amdgcn_mfma_f32_16x16x32_bf16(a, bb, wt[nt], 0, 0, 0);
        }
        if (w >= 4) {
            #pragma unroll
            for (int nt = 4; nt < 8; nt++) {
                bf16x8 bb = *(const bf16x8*)&kb[16 * nt + l15][quad * 8 + ks * 32];
                wt[nt] = __builtin_amdgcn_mfma_f32_16x16x32_bf16(a, bb, wt[nt], 0, 0, 0);
            }
        }
    }
    __syncthreads();   // all waves done reading qb/kb -> safe to overwrite with W

    // mask, round to bf16, rowsum (of rounded values!), store W:
    //   s < 64 -> kb region (Wlo),  s >= 64 -> qb region (Whi, waves 4-7 only)
    {
        const int tbase = 16 * w + quad * 4;               // chunk-local t of reg r=0
        float rsum[4] = {0.f, 0.f, 0.f, 0.f};
        #pragma unroll
        for (int nt = 0; nt < 4; nt++) {
            const int s = 16 * nt + l15;
            #pragma unroll
            for (int r = 0; r < 4; r++) {
                float val = (s > tbase + r) ? 0.f : wt[nt][r];
                unsigned short wb16 = f2b(val);
                kb[tbase + r][s] = wb16;
                rsum[r] += b2f(wb16);
            }
        }
        if (w >= 4) {
            #pragma unroll
            for (int nt = 4; nt < 8; nt++) {
                const int s = 16 * nt + l15;
                #pragma unroll
                for (int r = 0; r < 4; r++) {
                    float val = (s > tbase + r) ? 0.f : wt[nt][r];
                    unsigned short wb16 = f2b(val);
                    qb[tbase + r][s - 64] = wb16;
                    rsum[r] += b2f(wb16);
                }
            }
        }
        #pragma unroll
        for (int r = 0; r < 4; r++) {
            float rs = rsum[r];
            rs += __shfl_xor(rs, 8, 16);
            rs += __shfl_xor(rs, 4, 16);
            rs += __shfl_xor(rs, 2, 16);
            rs += __shfl_xor(rs, 1, 16);
            if (l15 == 0) den[tbase + r] += rs;
        }
    }
    __syncthreads();   // W + den visible

    // GEMM3: acc[t][e] += W[t][s] * V[s][e].  Waves 0-3 skip s>=64 (W is zero).
    #pragma unroll
    for (int ks = 0; ks < 2; ks++) {
        bf16x8 a = *(const bf16x8*)&kb[16 * w + l15][quad * 8 + ks * 32];
        #pragma unroll
        for (int nt = 0; nt < 4; nt++) {
            bf16x8 bb = *(const bf16x8*)&vb[16 * nt + l15][quad * 8 + ks * 32];
            acc[nt] = __builtin_amdgcn_mfma_f32_16x16x32_bf16(a, bb, acc[nt], 0, 0, 0);
        }
    }
    if (w >= 4) {
        #pragma unroll
        for (int ks = 2; ks < 4; ks++) {
            bf16x8 a = *(const bf16x8*)&qb[16 * w + l15][quad * 8 + (ks - 2) * 32];
            #pragma unroll
            for (int nt = 0; nt < 4; nt++) {
                bf16x8 bb = *(const bf16x8*)&vb[16 * nt + l15][quad * 8 + ks * 32];
                acc[nt] = __builtin_amdgcn_mfma_f32_16x16x32_bf16(a, bb, acc[nt], 0, 0, 0);
            }
        }
    }

    // epilogue: out[t][e] = acc / den[t]
    #pragma unroll
    for (int r = 0; r < 4; r++) {
        const int t = 16 * w + quad * 4 + r;
        const float inv = 1.0f / den[t];
        const size_t gbase = ((((size_t)b * Tc) + (t0 + t)) * Hc + h) * Dc;
        #pragma unroll
        for (int nt = 0; nt < 4; nt++) {
            outp[gbase + 16 * nt + l15] = acc[nt][r] * inv;
        }
    }
}

extern "C" void kernel_launch(void* const* d_in, const int* in_sizes, int n_in,
                              void* d_out, int out_size, void* d_ws, size_t ws_size,
                              hipStream_t stream) {
    const float* q = (const float*)d_in[0];
    const float* k = (const float*)d_in[1];
    const float* v = (const float*)d_in[2];
    float* out = (float*)d_out;
    float* ws  = (float*)d_ws;   // 4096*4160*4 = 68.2 MB

    k_chunksum<<<BHc * NCH, 256, 0, stream>>>(k, v, ws);
    dim3 g2(BHc, (REC + 255) / 256);
    k_prefix<<<g2, 256, 0, stream>>>(ws);
    k_output<<<BHc * NCH, 512, 0, stream>>>(q, k, v, ws, out);
}

// Round 6
// 501.342 us; speedup vs baseline: 1.0810x; 1.0303x over previous
//
#include <hip/hip_runtime.h>
#include <hip/hip_bf16.h>

// Causal linear attention (ELU+1), chunked 3-pass, bf16 MFMA formulation.
// B=4, T=8192, H=16, D=64, fp32 in/out.
// ws: 4096 records (bh*NCH+c) of REC=4160 fp32: S^T[e][d] (4096) then z[d] (64).
// ws requirement: 68.2 MB (unchanged).
//
// R2 design (resubmitted; three infra timeouts, still unmeasured):
//  - k_chunksum + k_prefix (full 64-long scan over ws, 136 MB extra traffic)
//    replaced by k_chunkscan (segmented scan: 1024 blocks = bh x 16 segments of
//    4 chunks; running S/z carried in MFMA accumulator registers; exclusive
//    local prefixes written directly; segment TOTAL stored in the first-chunk
//    record slot, which is identically zero in an exclusive scan)
//    + k_segscan (scans the 16 segment totals per bh, ~17 MB).
//  - k_output: adds the (L2-hot) segment base while staging sb/zsh. Otherwise
//    unchanged from R1.

#define EPS_ 1e-6f

constexpr int Bc  = 4;
constexpr int Tc  = 8192;
constexpr int Hc  = 16;
constexpr int Dc  = 64;
constexpr int CH  = 128;          // chunk length
constexpr int NCH = Tc / CH;      // 64
constexpr int BHc = Bc * Hc;      // 64
constexpr int REC = Dc * Dc + Dc; // 4160
constexpr int SEG = 16;           // segments per bh
constexpr int CPS = NCH / SEG;    // 4 chunks per segment

typedef short  bf16x8 __attribute__((ext_vector_type(8)));  // 8 bf16 (4 VGPRs)
typedef float  f32x4  __attribute__((ext_vector_type(4)));

__device__ __forceinline__ float phi_f(float x) {
    return x > 0.f ? x + 1.f : __expf(x);   // elu(x)+1
}
__device__ __forceinline__ unsigned short f2b(float x) {
    __hip_bfloat16 b = __float2bfloat16(x);          // round-to-nearest-even
    return __builtin_bit_cast(unsigned short, b);
}
__device__ __forceinline__ float b2f(unsigned short u) {
    return __uint_as_float(((unsigned)u) << 16);     // exact
}

// ---- pass 1: segmented scan.  Block (bh,seg) walks its CPS chunks serially,
//      acc registers carry running S^T; writes EXCLUSIVE local prefix records;
//      segment total goes into record slot of chunk seg*CPS (local prefix there
//      is identically 0 and is reconstructed in pass 3).
__global__ __launch_bounds__(256, 4) void k_chunkscan(const float* __restrict__ kin,
                                                      const float* __restrict__ vin,
                                                      float* __restrict__ ws) {
    const int blk = blockIdx.x;              // bh*SEG + seg
    const int bh  = blk >> 4, seg = blk & (SEG - 1);
    const int b   = bh >> 4,  h   = bh & 15;
    const int tid = threadIdx.x;
    const int w = tid >> 6, lane = tid & 63;
    const int l15 = lane & 15, quad = lane >> 4;

    __shared__ unsigned short ktr[64][136];  // phiK^T [d][s], s=0..127
    __shared__ unsigned short vtr[64][136];  // V^T    [e][s]
    __shared__ float zred[16][64];           // z partials [rowgroup][d]

    const int c0 = (tid & 15) << 2;          // d/e col group 0..60
    const int rl = (tid >> 4) << 2;          // row group 0..60

    f32x4 acc[4];
    #pragma unroll
    for (int nt = 0; nt < 4; nt++) acc[nt] = (f32x4){0.f, 0.f, 0.f, 0.f};
    float zrun = 0.f;                        // running z[d=tid] (tid<64)

    for (int i = 0; i < CPS; ++i) {
        const int c  = seg * CPS + i;
        const int t0 = c * CH;

        // load + phi + bf16-round + register 4x4 transpose; z partials from regs
        unsigned short hk[2][4][4], hv[2][4][4];
        float zp[4] = {0.f, 0.f, 0.f, 0.f};
        #pragma unroll
        for (int sh = 0; sh < 2; ++sh) {
            const int r0 = rl + sh * 64;
            #pragma unroll
            for (int jj = 0; jj < 4; ++jj) {
                const size_t g = ((((size_t)b * Tc) + (t0 + r0 + jj)) * Hc + h) * Dc + c0;
                const float4 kk = *(const float4*)(kin + g);
                const float4 vv = *(const float4*)(vin + g);
                hk[sh][jj][0] = f2b(phi_f(kk.x)); hk[sh][jj][1] = f2b(phi_f(kk.y));
                hk[sh][jj][2] = f2b(phi_f(kk.z)); hk[sh][jj][3] = f2b(phi_f(kk.w));
                hv[sh][jj][0] = f2b(vv.x); hv[sh][jj][1] = f2b(vv.y);
                hv[sh][jj][2] = f2b(vv.z); hv[sh][jj][3] = f2b(vv.w);
                #pragma unroll
                for (int j = 0; j < 4; ++j) zp[j] += b2f(hk[sh][jj][j]);
            }
        }
        __syncthreads();   // previous chunk's LDS consumers done

        #pragma unroll
        for (int sh = 0; sh < 2; ++sh) {
            const int r0 = rl + sh * 64;
            #pragma unroll
            for (int j = 0; j < 4; ++j) {
                *(ushort4*)&ktr[c0 + j][r0] =
                    make_ushort4(hk[sh][0][j], hk[sh][1][j], hk[sh][2][j], hk[sh][3][j]);
                *(ushort4*)&vtr[c0 + j][r0] =
                    make_ushort4(hv[sh][0][j], hv[sh][1][j], hv[sh][2][j], hv[sh][3][j]);
            }
        }
        #pragma unroll
        for (int j = 0; j < 4; ++j) zred[tid >> 4][c0 + j] = zp[j];

        // exclusive record for this chunk (register data, overlaps LDS writes)
        float* rec = ws + (size_t)(bh * NCH + c) * REC;
        if (i > 0) {
            #pragma unroll
            for (int nt = 0; nt < 4; nt++)
                #pragma unroll
                for (int r = 0; r < 4; r++)
                    rec[(16 * w + quad * 4 + r) * 64 + 16 * nt + l15] = acc[nt][r];
        }
        __syncthreads();   // ktr/vtr/zred visible

        if (tid < 64) {
            if (i > 0) rec[4096 + tid] = zrun;      // exclusive z
            float zs = 0.f;
            #pragma unroll
            for (int g = 0; g < 16; g++) zs += zred[g][tid];
            zrun += zs;
        }

        // S^T accumulate: acc[e][d] += V^T[e][s] * phiK[s][d]
        #pragma unroll
        for (int ks = 0; ks < 4; ks++) {
            bf16x8 a = *(const bf16x8*)&vtr[16 * w + l15][quad * 8 + ks * 32];
            #pragma unroll
            for (int nt = 0; nt < 4; nt++) {
                bf16x8 bb = *(const bf16x8*)&ktr[16 * nt + l15][quad * 8 + ks * 32];
                acc[nt] = __builtin_amdgcn_mfma_f32_16x16x32_bf16(a, bb, acc[nt], 0, 0, 0);
            }
        }
    }

    // segment totals -> first-chunk record slot
    {
        float* rec0 = ws + (size_t)(bh * NCH + seg * CPS) * REC;
        #pragma unroll
        for (int nt = 0; nt < 4; nt++)
            #pragma unroll
            for (int r = 0; r < 4; r++)
                rec0[(16 * w + quad * 4 + r) * 64 + 16 * nt + l15] = acc[nt][r];
        if (tid < 64) rec0[4096 + tid] = zrun;
    }
}

// ---- pass 2: exclusive scan over the SEG segment totals per bh (elementwise).
//      Reads/writes only the SEG total-slots (record of chunk seg*CPS).
__global__ __launch_bounds__(256) void k_segscan(float* __restrict__ ws) {
    const int bh = blockIdx.x;
    const int e  = blockIdx.y * 256 + threadIdx.x;
    if (e >= REC) return;
    float* p = ws + (size_t)bh * NCH * REC + e;
    float t[SEG];
    #pragma unroll
    for (int s = 0; s < SEG; ++s) t[s] = p[(size_t)(s * CPS) * REC];
    float run = 0.f;
    #pragma unroll
    for (int s = 0; s < SEG; ++s) { p[(size_t)(s * CPS) * REC] = run; run += t[s]; }
}

// ---------------- pass 3: outputs, one 512-thread block per FULL chunk ------------
__global__ __launch_bounds__(512, 4) void k_output(const float* __restrict__ qin,
                                                   const float* __restrict__ kin,
                                                   const float* __restrict__ vin,
                                                   const float* __restrict__ ws,
                                                   float* __restrict__ outp) {
    const int chunk = blockIdx.x;                // bh*NCH + c
    const int bh = chunk >> 6, c = chunk & (NCH - 1);
    const int b = bh >> 4, h = bh & 15;
    const int t0 = c * CH;
    const int tid = threadIdx.x;
    const int w = tid >> 6, lane = tid & 63;
    const int l15 = lane & 15, quad = lane >> 4;

    __shared__ unsigned short qb[128][72];  // phiQ [t][d]; cols reused as W[t][64+s']
    __shared__ unsigned short kb[128][72];  // phiK [s][d]; reused as W[t][s<64]
    __shared__ unsigned short sb[64][72];   // S^T[e][d] (prefixed, bf16)
    __shared__ unsigned short vb[64][136];  // V^T [e][s], s=0..127
    __shared__ float zsh[64];
    __shared__ float den[128];

    // ---- stage phi(q), phi(k) natural (128 rows, 512 threads: one row each 1/4) --
    {
        const int row = tid >> 2, cb = (tid & 3) << 4;
        const size_t g = ((((size_t)b * Tc) + (t0 + row)) * Hc + h) * Dc + cb;
        const float4* qp = (const float4*)(qin + g);
        const float4* kp = (const float4*)(kin + g);
        #pragma unroll
        for (int i = 0; i < 4; i++) {
            float4 qq = qp[i];
            float4 kk = kp[i];
            *(ushort4*)&qb[row][cb + 4 * i] =
                make_ushort4(f2b(phi_f(qq.x)), f2b(phi_f(qq.y)), f2b(phi_f(qq.z)), f2b(phi_f(qq.w)));
            *(ushort4*)&kb[row][cb + 4 * i] =
                make_ushort4(f2b(phi_f(kk.x)), f2b(phi_f(kk.y)), f2b(phi_f(kk.z)), f2b(phi_f(kk.w)));
        }
    }
    // ---- stage V^T via in-register 4x4 transpose (128 rows x 64 cols, one pass) --
    {
        const int c0 = (tid & 15) << 2;          // e-col group 0..60
        const int r0 = (tid >> 4) << 2;          // s-row group 0..124
        unsigned short hv[4][4];
        #pragma unroll
        for (int jj = 0; jj < 4; ++jj) {
            const size_t g = ((((size_t)b * Tc) + (t0 + r0 + jj)) * Hc + h) * Dc + c0;
            const float4 vv = *(const float4*)(vin + g);
            hv[jj][0] = f2b(vv.x); hv[jj][1] = f2b(vv.y);
            hv[jj][2] = f2b(vv.z); hv[jj][3] = f2b(vv.w);
        }
        #pragma unroll
        for (int j = 0; j < 4; ++j)
            *(ushort4*)&vb[c0 + j][r0] = make_ushort4(hv[0][j], hv[1][j], hv[2][j], hv[3][j]);
    }
    // ---- stage (local prefix + segment base) -> sb (bf16), z -> zsh (fp32) ------
    {
        const float* rec = ws + (size_t)chunk * REC;
        const float* bse = ws + (size_t)(bh * NCH + (c & ~(CPS - 1))) * REC;
        const bool cz = ((c & (CPS - 1)) == 0);   // this record IS the base slot
        #pragma unroll
        for (int i = 0; i < 2; i++) {
            const int idx = tid + i * 512;       // float4 index, 0..1023
            float4 sv = ((const float4*)rec)[idx];
            float4 bv = ((const float4*)bse)[idx];
            float4 t;
            if (cz) t = bv;
            else { t.x = sv.x + bv.x; t.y = sv.y + bv.y; t.z = sv.z + bv.z; t.w = sv.w + bv.w; }
            const int flat = idx * 4, e = flat >> 6, d = flat & 63;
            *(ushort4*)&sb[e][d] = make_ushort4(f2b(t.x), f2b(t.y), f2b(t.z), f2b(t.w));
        }
        if (tid < 16) {
            float4 zv = ((const float4*)(rec + 4096))[tid];
            float4 bz = ((const float4*)(bse + 4096))[tid];
            float4 t;
            if (cz) t = bz;
            else { t.x = zv.x + bz.x; t.y = zv.y + bz.y; t.z = zv.z + bz.z; t.w = zv.w + bz.w; }
            zsh[tid * 4 + 0] = t.x; zsh[tid * 4 + 1] = t.y;
            zsh[tid * 4 + 2] = t.z; zsh[tid * 4 + 3] = t.w;
        }
    }
    __syncthreads();

    // den0 = eps + phiQ[t] . z
    if (tid < 128) {
        float s = 0.f;
        #pragma unroll
        for (int j = 0; j < 8; j++) {
            bf16x8 qv = *(const bf16x8*)&qb[tid][j * 8];
            #pragma unroll
            for (int u = 0; u < 8; u++) s += b2f((unsigned short)qv[u]) * zsh[j * 8 + u];
        }
        den[tid] = s + EPS_;
    }

    // GEMM1: acc[t][e] = phiQ[t][d] * S[d][e]   (B from S^T rows)
    f32x4 acc[4];
    #pragma unroll
    for (int nt = 0; nt < 4; nt++) acc[nt] = (f32x4){0.f, 0.f, 0.f, 0.f};
    #pragma unroll
    for (int ks = 0; ks < 2; ks++) {
        bf16x8 a = *(const bf16x8*)&qb[16 * w + l15][quad * 8 + ks * 32];
        #pragma unroll
        for (int nt = 0; nt < 4; nt++) {
            bf16x8 bb = *(const bf16x8*)&sb[16 * nt + l15][quad * 8 + ks * 32];
            acc[nt] = __builtin_amdgcn_mfma_f32_16x16x32_bf16(a, bb, acc[nt], 0, 0, 0);
        }
    }

    // GEMM2: W[t][s] = phiQ[t][d] * phiK[s][d].  Waves 0-3 (t<64) skip s>=64
    // (fully masked).  wt[nt] covers s = 16*nt + l15.
    f32x4 wt[8];
    #pragma unroll
    for (int nt = 0; nt < 8; nt++) wt[nt] = (f32x4){0.f, 0.f, 0.f, 0.f};
    #pragma unroll
    for (int ks = 0; ks < 2; ks++) {
        bf16x8 a = *(const bf16x8*)&qb[16 * w + l15][quad * 8 + ks * 32];
        #pragma unroll
        for (int nt = 0; nt < 4; nt++) {
            bf16x8 bb = *(const bf16x8*)&kb[16 * nt + l15][quad * 8 + ks * 32];
            wt[nt] = __builtin_amdgcn_mfma_f32_16x16x32_bf16(a, bb, wt[nt], 0, 0, 0);
        }
        if (w >= 4) {
            #pragma unroll
            for (int nt = 4; nt < 8; nt++) {
                bf16x8 bb = *(const bf16x8*)&kb[16 * nt + l15][quad * 8 + ks * 32];
                wt[nt] = __builtin_amdgcn_mfma_f32_16x16x32_bf16(a, bb, wt[nt], 0, 0, 0);
            }
        }
    }
    __syncthreads();   // all waves done reading qb/kb -> safe to overwrite with W

    // mask, round to bf16, rowsum (of rounded values!), store W:
    //   s < 64 -> kb region (Wlo),  s >= 64 -> qb region (Whi, waves 4-7 only)
    {
        const int tbase = 16 * w + quad * 4;               // chunk-local t of reg r=0
        float rsum[4] = {0.f, 0.f, 0.f, 0.f};
        #pragma unroll
        for (int nt = 0; nt < 4; nt++) {
            const int s = 16 * nt + l15;
            #pragma unroll
            for (int r = 0; r < 4; r++) {
                float val = (s > tbase + r) ? 0.f : wt[nt][r];
                unsigned short wb16 = f2b(val);
                kb[tbase + r][s] = wb16;
                rsum[r] += b2f(wb16);
            }
        }
        if (w >= 4) {
            #pragma unroll
            for (int nt = 4; nt < 8; nt++) {
                const int s = 16 * nt + l15;
                #pragma unroll
                for (int r = 0; r < 4; r++) {
                    float val = (s > tbase + r) ? 0.f : wt[nt][r];
                    unsigned short wb16 = f2b(val);
                    qb[tbase + r][s - 64] = wb16;
                    rsum[r] += b2f(wb16);
                }
            }
        }
        #pragma unroll
        for (int r = 0; r < 4; r++) {
            float rs = rsum[r];
            rs += __shfl_xor(rs, 8, 16);
            rs += __shfl_xor(rs, 4, 16);
            rs += __shfl_xor(rs, 2, 16);
            rs += __shfl_xor(rs, 1, 16);
            if (l15 == 0) den[tbase + r] += rs;
        }
    }
    __syncthreads();   // W + den visible

    // GEMM3: acc[t][e] += W[t][s] * V[s][e].  Waves 0-3 skip s>=64 (W is zero).
    #pragma unroll
    for (int ks = 0; ks < 2; ks++) {
        bf16x8 a = *(const bf16x8*)&kb[16 * w + l15][quad * 8 + ks * 32];
        #pragma unroll
        for (int nt = 0; nt < 4; nt++) {
            bf16x8 bb = *(const bf16x8*)&vb[16 * nt + l15][quad * 8 + ks * 32];
            acc[nt] = __builtin_amdgcn_mfma_f32_16x16x32_bf16(a, bb, acc[nt], 0, 0, 0);
        }
    }
    if (w >= 4) {
        #pragma unroll
        for (int ks = 2; ks < 4; ks++) {
            bf16x8 a = *(const bf16x8*)&qb[16 * w + l15][quad * 8 + (ks - 2) * 32];
            #pragma unroll
            for (int nt = 0; nt < 4; nt++) {
                bf16x8 bb = *(const bf16x8*)&vb[16 * nt + l15][quad * 8 + ks * 32];
                acc[nt] = __builtin_amdgcn_mfma_f32_16x16x32_bf16(a, bb, acc[nt], 0, 0, 0);
            }
        }
    }

    // epilogue: out[t][e] = acc / den[t]
    #pragma unroll
    for (int r = 0; r < 4; r++) {
        const int t = 16 * w + quad * 4 + r;
        const float inv = 1.0f / den[t];
        const size_t gbase = ((((size_t)b * Tc) + (t0 + t)) * Hc + h) * Dc;
        #pragma unroll
        for (int nt = 0; nt < 4; nt++) {
            outp[gbase + 16 * nt + l15] = acc[nt][r] * inv;
        }
    }
}

extern "C" void kernel_launch(void* const* d_in, const int* in_sizes, int n_in,
                              void* d_out, int out_size, void* d_ws, size_t ws_size,
                              hipStream_t stream) {
    const float* q = (const float*)d_in[0];
    const float* k = (const float*)d_in[1];
    const float* v = (const float*)d_in[2];
    float* out = (float*)d_out;
    float* ws  = (float*)d_ws;   // 4096*4160*4 = 68.2 MB

    k_chunkscan<<<BHc * SEG, 256, 0, stream>>>(k, v, ws);
    dim3 g2(BHc, (REC + 255) / 256);
    k_segscan<<<g2, 256, 0, stream>>>(ws);
    k_output<<<BHc * NCH, 512, 0, stream>>>(q, k, v, ws, out);
}